// Round 5
// baseline (201.651 us; speedup 1.0000x reference)
//
#include <hip/hip_runtime.h>
#include <cstddef>
#include <cstdint>

#define B_ 2
#define S_ 2048
#define DM_ 1024
#define H_ 16
#define DH_ 64
#define NEGV (-1e12f)
// log2(e) / sqrt(DH) folded into Q at projection epilogue
#define QSCALE 0.18033688011112042f

typedef __attribute__((ext_vector_type(8))) short bf16x8;
typedef __attribute__((ext_vector_type(4))) float f32x4;

__device__ __forceinline__ unsigned short f2bf(float f) {
    union { float f; uint32_t u; } v; v.f = f;
    uint32_t u = v.u;
    u += 0x7FFF + ((u >> 16) & 1);   // round-to-nearest-even
    return (unsigned short)(u >> 16);
}

// packed f32x2 -> bf16x2 (RNE), single HW instruction (T12 recipe)
__device__ __forceinline__ uint32_t cvt_pk_bf16(float lo, float hi) {
    uint32_t r;
    asm volatile("v_cvt_pk_bf16_f32 %0, %1, %2" : "=v"(r) : "v"(lo), "v"(hi));
    return r;
}

__device__ __forceinline__ void gload_lds16(const void* g, void* l) {
    __builtin_amdgcn_global_load_lds(
        (__attribute__((address_space(1))) void*)g,
        (__attribute__((address_space(3))) void*)l,
        16, 0, 0);
}

// ---------------------------------------------------------------------------
// x (fp32) -> bf16, flat
// ---------------------------------------------------------------------------
__global__ __launch_bounds__(256) void convx_kernel(
    const float* __restrict__ x, ushort* __restrict__ xb)
{
    const size_t i = ((size_t)blockIdx.x * 256 + threadIdx.x) * 8;
    const float4 a = *(const float4*)(x + i);
    const float4 b = *(const float4*)(x + i + 4);
    ushort4 u0, u1;
    u0.x = f2bf(a.x); u0.y = f2bf(a.y); u0.z = f2bf(a.z); u0.w = f2bf(a.w);
    u1.x = f2bf(b.x); u1.y = f2bf(b.y); u1.z = f2bf(b.z); u1.w = f2bf(b.w);
    *(ushort4*)(xb + i) = u0;
    *(ushort4*)(xb + i + 4) = u1;
}

// ---------------------------------------------------------------------------
// W[k][n] fp32 -> Wt[n][k] bf16 (64x64 LDS-tiled transpose)
// ---------------------------------------------------------------------------
__global__ __launch_bounds__(256) void wconv_kernel(
    const float* __restrict__ W, ushort* __restrict__ Wt)
{
    __shared__ float T[64][65];
    const int tid = threadIdx.x;
    const int n0 = (blockIdx.x & 15) * 64;
    const int k0 = (blockIdx.x >> 4) * 64;
    const int tr = tid >> 4, tc = tid & 15;
#pragma unroll
    for (int i = 0; i < 4; ++i) {
        const float4 v = *(const float4*)(W + (size_t)(k0 + tr + i * 16) * 1024 + n0 + tc * 4);
        T[tr + i * 16][tc * 4 + 0] = v.x;
        T[tr + i * 16][tc * 4 + 1] = v.y;
        T[tr + i * 16][tc * 4 + 2] = v.z;
        T[tr + i * 16][tc * 4 + 3] = v.w;
    }
    __syncthreads();
    const int orr = tid >> 2, oc = tid & 3;
#pragma unroll
    for (int j = 0; j < 4; ++j) {
        ushort4 u;
        u.x = f2bf(T[oc * 16 + j * 4 + 0][orr]);
        u.y = f2bf(T[oc * 16 + j * 4 + 1][orr]);
        u.z = f2bf(T[oc * 16 + j * 4 + 2][orr]);
        u.w = f2bf(T[oc * 16 + j * 4 + 3][orr]);
        *(ushort4*)(Wt + (size_t)(n0 + orr) * 1024 + k0 + oc * 16 + j * 4) = u;
    }
}

// ---------------------------------------------------------------------------
// bf16 MFMA GEMM, C = A @ Bt^T (+bias, +epilogue). A[M][1024], Bt[n][1024].
// MODE 1: fused QKV (BM=128, Ntot=3072 in 3 segments; rope epilogues, V transp)
// MODE 0: out-proj  (BM=64, N=1024, fp32 out)
// (unchanged from round 4 — validated)
// ---------------------------------------------------------------------------
template <int MODE>
__global__ __launch_bounds__(256) void gemm_bf16(
    const ushort* __restrict__ A,
    const ushort* __restrict__ B0, const ushort* __restrict__ B1, const ushort* __restrict__ B2,
    const float* __restrict__ bias0, const float* __restrict__ bias1, const float* __restrict__ bias2,
    const float* __restrict__ pos,
    void* __restrict__ o0, void* __restrict__ o1, void* __restrict__ o2)
{
    constexpr int BM = MODE ? 128 : 64;
    constexpr int BN = 128;
    constexpr int NTN = MODE ? 24 : 8;
    constexpr int A_ISS = BM / 64;
    constexpr int ABYTES = BM * 64;
    constexpr int WM = MODE ? 2 : 1;
    constexpr int TM = BM / WM;
    constexpr int TN = BN / (4 / WM);
    constexpr int MI = TM / 16;
    constexpr int NJ = TN / 16;
    constexpr int NT = DM_ / 32;

    __shared__ char lds[2][(BM + BN) * 64];

    const int tid  = threadIdx.x;
    const int lane = tid & 63;
    const int lc = lane & 15, lg = lane >> 4;
    const int w  = tid >> 6;
    const int wm = MODE ? (w >> 1) : 0;
    const int wn = MODE ? (w & 1) : w;

    const int ntile = blockIdx.x % NTN;
    const int mtile = blockIdx.x / NTN;
    const int m0 = mtile * BM;

    int seg = 0, nseg0 = ntile * 128;
    const ushort* Bt = B0;
    const float* biasp = bias0;
    if constexpr (MODE == 1) {
        seg = ntile >> 3;
        nseg0 = (ntile & 7) * 128;
        Bt = (seg == 0) ? B0 : (seg == 1) ? B1 : B2;
        biasp = (seg == 0) ? bias0 : (seg == 1) ? bias1 : bias2;
    }

    const int sr = tid >> 2;
    const int sc = (tid & 3) * 8;
    const int wub = (tid & 0xC0) * 16;

#define STAGE(BUF, KT)                                                             \
    do {                                                                           \
        const int k0s = (KT) * 32;                                                 \
        char* lb = &lds[BUF][0];                                                   \
        _Pragma("unroll")                                                          \
        for (int ii = 0; ii < A_ISS; ++ii)                                         \
            gload_lds16(A + (size_t)(m0 + ii * 64 + sr) * DM_ + k0s + sc,          \
                        lb + ii * 4096 + wub);                                     \
        _Pragma("unroll")                                                          \
        for (int ii = 0; ii < 2; ++ii)                                             \
            gload_lds16(Bt + (size_t)(nseg0 + ii * 64 + sr) * DM_ + k0s + sc,      \
                        lb + ABYTES + ii * 4096 + wub);                            \
    } while (0)

    f32x4 acc[MI][NJ];
#pragma unroll
    for (int mi = 0; mi < MI; ++mi)
#pragma unroll
        for (int nj = 0; nj < NJ; ++nj) acc[mi][nj] = (f32x4){0.f, 0.f, 0.f, 0.f};

    STAGE(0, 0);

    for (int kt = 0; kt < NT; ++kt) {
        const int cur = kt & 1;
        __syncthreads();
        if (kt + 1 < NT) STAGE(cur ^ 1, kt + 1);
        const char* Ab = &lds[cur][0];
        const char* Bb = Ab + ABYTES;
        bf16x8 af[MI], bfr[NJ];
#pragma unroll
        for (int mi = 0; mi < MI; ++mi)
            af[mi] = *(const bf16x8*)(Ab + (wm * TM + mi * 16 + lc) * 64 + lg * 16);
#pragma unroll
        for (int nj = 0; nj < NJ; ++nj)
            bfr[nj] = *(const bf16x8*)(Bb + (wn * TN + nj * 16 + lc) * 64 + lg * 16);
#pragma unroll
        for (int mi = 0; mi < MI; ++mi)
#pragma unroll
            for (int nj = 0; nj < NJ; ++nj)
                acc[mi][nj] = __builtin_amdgcn_mfma_f32_16x16x32_bf16(af[mi], bfr[nj], acc[mi][nj], 0, 0, 0);
    }
#undef STAGE

    if constexpr (MODE == 0) {
        float* C = (float*)o0;
#pragma unroll
        for (int nj = 0; nj < NJ; ++nj) {
            const int n = nseg0 + wn * TN + nj * 16 + lc;
            const float bn = biasp[n];
#pragma unroll
            for (int mi = 0; mi < MI; ++mi)
#pragma unroll
                for (int r = 0; r < 4; ++r) {
                    const int m = m0 + wm * TM + mi * 16 + lg * 4 + r;
                    C[(size_t)m * DM_ + n] = acc[mi][nj][r] + bn;
                }
        }
    } else {
        if (seg < 2) {
            ushort* C = (seg == 0) ? (ushort*)o0 : (ushort*)o1;
#pragma unroll
            for (int nj = 0; nj < NJ; ++nj) {
                const int n = nseg0 + wn * TN + nj * 16 + lc;
                const float bn = biasp[n];
                const int i2 = (n & 63) & ~1;
                const bool odd = (n & 1) != 0;
#pragma unroll
                for (int mi = 0; mi < MI; ++mi)
#pragma unroll
                    for (int r = 0; r < 4; ++r) {
                        const int m = m0 + wm * TM + mi * 16 + lg * 4 + r;
                        const int s = m & (S_ - 1);
                        const float2 pz = *(const float2*)(pos + (size_t)s * DH_ + i2);
                        const float v = acc[mi][nj][r] + bn;
                        const float pv = __shfl_xor(v, 1);
                        float ov = odd ? (v * pz.y + pv * pz.x) : (v * pz.y - pv * pz.x);
                        if (seg == 0) ov *= QSCALE;
                        C[(size_t)m * (H_ * DH_) + n] = f2bf(ov);
                    }
            }
        } else {
            ushort* C = (ushort*)o2;
#pragma unroll
            for (int nj = 0; nj < NJ; ++nj) {
                const int n = nseg0 + wn * TN + nj * 16 + lc;
                const int hh = n >> 6, dd = n & 63;
                const float bn = biasp[n];
#pragma unroll
                for (int mi = 0; mi < MI; ++mi) {
                    const int mb = m0 + wm * TM + mi * 16 + lg * 4;
                    const int bb = mb >> 11, ss = mb & (S_ - 1);
                    ushort4 u;
                    u.x = f2bf(acc[mi][nj][0] + bn);
                    u.y = f2bf(acc[mi][nj][1] + bn);
                    u.z = f2bf(acc[mi][nj][2] + bn);
                    u.w = f2bf(acc[mi][nj][3] + bn);
                    *(ushort4*)(C + ((size_t)(bb * H_ + hh) * DH_ + dd) * S_ + ss) = u;
                }
            }
        }
    }
}

// ---------------------------------------------------------------------------
// bf16 MFMA flash attention — round 5: cvt_pk P-packing (T12), defer-max
// rescale skip (T13, THR=0 -> exact semantics), setprio around MFMA (T5).
// Double-buffered LDS, one barrier per tile (race-free by construction).
// ---------------------------------------------------------------------------
__global__ __launch_bounds__(256) void attn_mfma_kernel(
    const short* __restrict__ Qb, const short* __restrict__ Kb,
    const short* __restrict__ Vt, const int* __restrict__ vmask,
    ushort* __restrict__ O)
{
    __shared__ short Ks[2][64 * 64];
    __shared__ short Vs[2][64 * 64];
    __shared__ float bias_s[2][64];

    const int tid  = threadIdx.x;
    const int lane = tid & 63;
    const int w    = tid >> 6;
    const int c    = lane & 15;
    const int g    = lane >> 4;

    const int bid = blockIdx.x;          // b*512 + h*32 + qc
    const int qc = bid & 31;
    const int h  = (bid >> 5) & 15;
    const int b  = bid >> 9;
    const int s0 = qc * 64;

    bf16x8 qf[2];
    {
        const size_t qbase = ((size_t)(b * S_ + s0 + w * 16 + c)) * DM_ + h * DH_ + g * 8;
        qf[0] = *(const bf16x8*)(Qb + qbase);
        qf[1] = *(const bf16x8*)(Qb + qbase + 32);
    }

    const int kr0 = tid >> 3, kc0 = tid & 7;
    const int kr1 = kr0 + 32;
    const size_t kpan = ((size_t)b * S_) * DM_ + h * DH_;
    const size_t vpan = ((size_t)(b * H_ + h) * DH_) * S_;

    uint4 kv0, kv1, vv0, vv1;
    int mskv = 1;

#define LOAD_TILE(KT)                                                            \
    do {                                                                         \
        const size_t kg = kpan + (size_t)((KT) * 64) * DM_;                      \
        kv0 = *(const uint4*)(Kb + kg + (size_t)kr0 * DM_ + kc0 * 8);            \
        kv1 = *(const uint4*)(Kb + kg + (size_t)kr1 * DM_ + kc0 * 8);            \
        const size_t vg = vpan + (KT) * 64;                                      \
        vv0 = *(const uint4*)(Vt + vg + (size_t)kr0 * S_ + kc0 * 8);             \
        vv1 = *(const uint4*)(Vt + vg + (size_t)kr1 * S_ + kc0 * 8);             \
        if (tid < 64) mskv = vmask[b * S_ + (KT) * 64 + tid];                    \
    } while (0)

    LOAD_TILE(0);

    float m_run = -1e30f, l_run = 0.f;
    f32x4 acc_o[4];
#pragma unroll
    for (int dg = 0; dg < 4; ++dg) acc_o[dg] = (f32x4){0.f, 0.f, 0.f, 0.f};

    const int srcA = ((((g & 1) * 2) << 4) + c) * 4;
    const int srcB = ((((g & 1) * 2 + 1) << 4) + c) * 4;
    const bool hiSel = (lane >= 32);

    for (int kt = 0; kt < S_ / 64; ++kt) {
        const int cur = kt & 1;
        *(uint4*)&Ks[cur][kr0 * 64 + ((kc0 ^ (kr0 & 7)) * 8)] = kv0;
        *(uint4*)&Ks[cur][kr1 * 64 + ((kc0 ^ (kr1 & 7)) * 8)] = kv1;
        *(uint4*)&Vs[cur][kr0 * 64 + ((kc0 ^ (kr0 & 7)) * 8)] = vv0;
        *(uint4*)&Vs[cur][kr1 * 64 + ((kc0 ^ (kr1 & 7)) * 8)] = vv1;
        if (tid < 64) bias_s[cur][tid] = mskv ? 0.f : NEGV;
        __syncthreads();

        if (kt + 1 < S_ / 64) LOAD_TILE(kt + 1);

        // ---- QK^T (swapped): acc_t[km] holds S^T[key][q=c], init with mask bias
        f32x4 acc_t[4];
#pragma unroll
        for (int km = 0; km < 4; ++km)
            acc_t[km] = *(const f32x4*)&bias_s[cur][km * 16 + g * 4];
        __builtin_amdgcn_s_setprio(1);
#pragma unroll
        for (int km = 0; km < 4; ++km) {
            const int krow = km * 16 + c;
            const int swz = krow & 7;
#pragma unroll
            for (int t = 0; t < 2; ++t) {
                const bf16x8 kf = *(const bf16x8*)&Ks[cur][krow * 64 + (((t * 4 + g) ^ swz) * 8)];
                acc_t[km] = __builtin_amdgcn_mfma_f32_16x16x32_bf16(kf, qf[t], acc_t[km], 0, 0, 0);
            }
        }
        __builtin_amdgcn_s_setprio(0);

        // ---- online softmax for q = lane&15 (replicated across 4 lane-groups)
        float pm = -1e30f;
#pragma unroll
        for (int km = 0; km < 4; ++km)
#pragma unroll
            for (int r = 0; r < 4; ++r) pm = fmaxf(pm, acc_t[km][r]);
        pm = fmaxf(pm, __shfl_xor(pm, 16));
        pm = fmaxf(pm, __shfl_xor(pm, 32));

        // defer-max: skip rescale when no q-row in this wave has a new max
        // (THR=0: P values stay <= 1, exact online-softmax semantics)
        if (!__all(pm <= m_run)) {
            const float m_new = fmaxf(m_run, pm);
            const float sc = exp2f(m_run - m_new);
#pragma unroll
            for (int r = 0; r < 4; ++r) {
                const float scr = __shfl(sc, (lane & 48) | (g * 4 + r));
#pragma unroll
                for (int dg = 0; dg < 4; ++dg) acc_o[dg][r] *= scr;
            }
            l_run *= sc;
            m_run = m_new;
        }

        float p[16];
        float tsum = 0.f;
#pragma unroll
        for (int km = 0; km < 4; ++km)
#pragma unroll
            for (int r = 0; r < 4; ++r) {
                const float e = exp2f(acc_t[km][r] - m_run);
                p[km * 4 + r] = e;
                tsum += e;
            }
        tsum += __shfl_xor(tsum, 16);
        tsum += __shfl_xor(tsum, 32);
        l_run += tsum;

        // pack P to bf16 pairs with single-instruction cvt_pk (RNE)
        uint32_t pk[4][2];
#pragma unroll
        for (int km = 0; km < 4; ++km) {
            pk[km][0] = cvt_pk_bf16(p[km * 4 + 0], p[km * 4 + 1]);
            pk[km][1] = cvt_pk_bf16(p[km * 4 + 2], p[km * 4 + 3]);
        }

        // ---- P-fragment via bpermute (wave-local), then PV MFMAs
#pragma unroll
        for (int t = 0; t < 2; ++t) {
            uint32_t fw[4];
#pragma unroll
            for (int w2 = 0; w2 < 4; ++w2) {
                const int src = (w2 < 2) ? srcA : srcB;
                const uint32_t vlo = (uint32_t)__builtin_amdgcn_ds_bpermute(src, (int)pk[2 * t][w2 & 1]);
                const uint32_t vhi = (uint32_t)__builtin_amdgcn_ds_bpermute(src, (int)pk[2 * t + 1][w2 & 1]);
                fw[w2] = hiSel ? vhi : vlo;
            }
            union { uint32_t u[4]; bf16x8 v; } pf;
            pf.u[0] = fw[0]; pf.u[1] = fw[1]; pf.u[2] = fw[2]; pf.u[3] = fw[3];
            __builtin_amdgcn_s_setprio(1);
#pragma unroll
            for (int dg = 0; dg < 4; ++dg) {
                const int vrow = dg * 16 + c;
                const bf16x8 vf = *(const bf16x8*)&Vs[cur][vrow * 64 + (((t * 4 + g) ^ (vrow & 7)) * 8)];
                acc_o[dg] = __builtin_amdgcn_mfma_f32_16x16x32_bf16(pf.v, vf, acc_o[dg], 0, 0, 0);
            }
            __builtin_amdgcn_s_setprio(0);
        }
        __syncthreads();
    }
#undef LOAD_TILE

    const float linv = 1.0f / l_run;
#pragma unroll
    for (int r = 0; r < 4; ++r) {
        const float lr = __shfl(linv, (lane & 48) | (g * 4 + r));
        const int row = s0 + w * 16 + g * 4 + r;
        const size_t ob = ((size_t)(b * S_ + row)) * DM_ + h * DH_;
#pragma unroll
        for (int dg = 0; dg < 4; ++dg)
            O[ob + dg * 16 + c] = f2bf(acc_o[dg][r] * lr);
    }
}

// ---------------------------------------------------------------------------
extern "C" void kernel_launch(void* const* d_in, const int* in_sizes, int n_in,
                              void* d_out, int out_size, void* d_ws, size_t ws_size,
                              hipStream_t stream)
{
    const float* x     = (const float*)d_in[0];
    const int*   vmask = (const int*)d_in[1];
    const float* pos   = (const float*)d_in[2];
    const float* Wq    = (const float*)d_in[3];
    const float* bq    = (const float*)d_in[4];
    const float* Wk    = (const float*)d_in[5];
    const float* bk    = (const float*)d_in[6];
    const float* Wv    = (const float*)d_in[7];
    const float* bv    = (const float*)d_in[8];
    const float* Wo    = (const float*)d_in[9];
    const float* bo    = (const float*)d_in[10];
    float* out = (float*)d_out;

    const size_t MN = (size_t)(B_ * S_) * (H_ * DH_);   // 4M

    ushort* xb  = (ushort*)d_ws;          // 8 MB
    ushort* Wtq = xb + MN;                // 2 MB each
    ushort* Wtk = Wtq + 1024 * 1024;
    ushort* Wtv = Wtk + 1024 * 1024;
    ushort* Wto = Wtv + 1024 * 1024;
    ushort* Qb  = Wto + 1024 * 1024;      // 8 MB each
    ushort* Kb  = Qb + MN;
    ushort* Vt  = Kb + MN;
    ushort* Ob  = Vt + MN;

    convx_kernel<<<(int)(MN / 2048), 256, 0, stream>>>(x, xb);
    wconv_kernel<<<256, 256, 0, stream>>>(Wq, Wtq);
    wconv_kernel<<<256, 256, 0, stream>>>(Wk, Wtk);
    wconv_kernel<<<256, 256, 0, stream>>>(Wv, Wtv);
    wconv_kernel<<<256, 256, 0, stream>>>(Wo, Wto);

    // fused QKV: grid = (4096/128) m-tiles x 24 n-tiles = 768 blocks (3/CU)
    gemm_bf16<1><<<768, 256, 0, stream>>>(xb, Wtq, Wtk, Wtv, bq, bk, bv, pos,
                                          (void*)Qb, (void*)Kb, (void*)Vt);

    attn_mfma_kernel<<<B_ * H_ * (S_ / 64), 256, 0, stream>>>(
        (const short*)Qb, (const short*)Kb, (const short*)Vt, vmask, Ob);

    // out-proj: grid = (4096/64) x 8 = 512 blocks (2/CU)
    gemm_bf16<0><<<512, 256, 0, stream>>>(Ob, Wto, nullptr, nullptr, bo, nullptr, nullptr,
                                          nullptr, (void*)out, nullptr, nullptr);
}

// Round 6
// 194.988 us; speedup vs baseline: 1.0342x; 1.0342x over previous
//
#include <hip/hip_runtime.h>
#include <cstddef>
#include <cstdint>

#define B_ 2
#define S_ 2048
#define DM_ 1024
#define H_ 16
#define DH_ 64
#define NEGV (-1e12f)
// log2(e) / sqrt(DH) folded into Q at projection epilogue
#define QSCALE 0.18033688011112042f
// defer-max threshold in log2 units: P <= 2^12, l <= 2048*4096 -> fp32-safe
#define DEFER_THR 12.0f

typedef __attribute__((ext_vector_type(8))) short bf16x8;
typedef __attribute__((ext_vector_type(4))) float f32x4;

__device__ __forceinline__ unsigned short f2bf(float f) {
    union { float f; uint32_t u; } v; v.f = f;
    uint32_t u = v.u;
    u += 0x7FFF + ((u >> 16) & 1);   // round-to-nearest-even
    return (unsigned short)(u >> 16);
}

// packed f32x2 -> bf16x2 (RNE), single HW instruction (T12 recipe)
__device__ __forceinline__ uint32_t cvt_pk_bf16(float lo, float hi) {
    uint32_t r;
    asm volatile("v_cvt_pk_bf16_f32 %0, %1, %2" : "=v"(r) : "v"(lo), "v"(hi));
    return r;
}

__device__ __forceinline__ void gload_lds16(const void* g, void* l) {
    __builtin_amdgcn_global_load_lds(
        (__attribute__((address_space(1))) void*)g,
        (__attribute__((address_space(3))) void*)l,
        16, 0, 0);
}

// ---------------------------------------------------------------------------
// x (fp32) -> bf16, flat
// ---------------------------------------------------------------------------
__global__ __launch_bounds__(256) void convx_kernel(
    const float* __restrict__ x, ushort* __restrict__ xb)
{
    const size_t i = ((size_t)blockIdx.x * 256 + threadIdx.x) * 8;
    const float4 a = *(const float4*)(x + i);
    const float4 b = *(const float4*)(x + i + 4);
    ushort4 u0, u1;
    u0.x = f2bf(a.x); u0.y = f2bf(a.y); u0.z = f2bf(a.z); u0.w = f2bf(a.w);
    u1.x = f2bf(b.x); u1.y = f2bf(b.y); u1.z = f2bf(b.z); u1.w = f2bf(b.w);
    *(ushort4*)(xb + i) = u0;
    *(ushort4*)(xb + i + 4) = u1;
}

// ---------------------------------------------------------------------------
// W[k][n] fp32 -> Wt[n][k] bf16 (64x64 LDS-tiled transpose)
// ---------------------------------------------------------------------------
__global__ __launch_bounds__(256) void wconv_kernel(
    const float* __restrict__ W, ushort* __restrict__ Wt)
{
    __shared__ float T[64][65];
    const int tid = threadIdx.x;
    const int n0 = (blockIdx.x & 15) * 64;
    const int k0 = (blockIdx.x >> 4) * 64;
    const int tr = tid >> 4, tc = tid & 15;
#pragma unroll
    for (int i = 0; i < 4; ++i) {
        const float4 v = *(const float4*)(W + (size_t)(k0 + tr + i * 16) * 1024 + n0 + tc * 4);
        T[tr + i * 16][tc * 4 + 0] = v.x;
        T[tr + i * 16][tc * 4 + 1] = v.y;
        T[tr + i * 16][tc * 4 + 2] = v.z;
        T[tr + i * 16][tc * 4 + 3] = v.w;
    }
    __syncthreads();
    const int orr = tid >> 2, oc = tid & 3;
#pragma unroll
    for (int j = 0; j < 4; ++j) {
        ushort4 u;
        u.x = f2bf(T[oc * 16 + j * 4 + 0][orr]);
        u.y = f2bf(T[oc * 16 + j * 4 + 1][orr]);
        u.z = f2bf(T[oc * 16 + j * 4 + 2][orr]);
        u.w = f2bf(T[oc * 16 + j * 4 + 3][orr]);
        *(ushort4*)(Wt + (size_t)(n0 + orr) * 1024 + k0 + oc * 16 + j * 4) = u;
    }
}

// ---------------------------------------------------------------------------
// bf16 MFMA GEMM, C = A @ Bt^T (+bias, +epilogue). A[M][1024], Bt[n][1024].
// MODE 1: fused QKV (BM=128, Ntot=3072 in 3 segments; rope epilogues, V transp)
// MODE 0: out-proj  (BM=64, N=1024, fp32 out)
// (unchanged — validated)
// ---------------------------------------------------------------------------
template <int MODE>
__global__ __launch_bounds__(256) void gemm_bf16(
    const ushort* __restrict__ A,
    const ushort* __restrict__ B0, const ushort* __restrict__ B1, const ushort* __restrict__ B2,
    const float* __restrict__ bias0, const float* __restrict__ bias1, const float* __restrict__ bias2,
    const float* __restrict__ pos,
    void* __restrict__ o0, void* __restrict__ o1, void* __restrict__ o2)
{
    constexpr int BM = MODE ? 128 : 64;
    constexpr int BN = 128;
    constexpr int NTN = MODE ? 24 : 8;
    constexpr int A_ISS = BM / 64;
    constexpr int ABYTES = BM * 64;
    constexpr int WM = MODE ? 2 : 1;
    constexpr int TM = BM / WM;
    constexpr int TN = BN / (4 / WM);
    constexpr int MI = TM / 16;
    constexpr int NJ = TN / 16;
    constexpr int NT = DM_ / 32;

    __shared__ char lds[2][(BM + BN) * 64];

    const int tid  = threadIdx.x;
    const int lane = tid & 63;
    const int lc = lane & 15, lg = lane >> 4;
    const int w  = tid >> 6;
    const int wm = MODE ? (w >> 1) : 0;
    const int wn = MODE ? (w & 1) : w;

    const int ntile = blockIdx.x % NTN;
    const int mtile = blockIdx.x / NTN;
    const int m0 = mtile * BM;

    int seg = 0, nseg0 = ntile * 128;
    const ushort* Bt = B0;
    const float* biasp = bias0;
    if constexpr (MODE == 1) {
        seg = ntile >> 3;
        nseg0 = (ntile & 7) * 128;
        Bt = (seg == 0) ? B0 : (seg == 1) ? B1 : B2;
        biasp = (seg == 0) ? bias0 : (seg == 1) ? bias1 : bias2;
    }

    const int sr = tid >> 2;
    const int sc = (tid & 3) * 8;
    const int wub = (tid & 0xC0) * 16;

#define STAGE(BUF, KT)                                                             \
    do {                                                                           \
        const int k0s = (KT) * 32;                                                 \
        char* lb = &lds[BUF][0];                                                   \
        _Pragma("unroll")                                                          \
        for (int ii = 0; ii < A_ISS; ++ii)                                         \
            gload_lds16(A + (size_t)(m0 + ii * 64 + sr) * DM_ + k0s + sc,          \
                        lb + ii * 4096 + wub);                                     \
        _Pragma("unroll")                                                          \
        for (int ii = 0; ii < 2; ++ii)                                             \
            gload_lds16(Bt + (size_t)(nseg0 + ii * 64 + sr) * DM_ + k0s + sc,      \
                        lb + ABYTES + ii * 4096 + wub);                            \
    } while (0)

    f32x4 acc[MI][NJ];
#pragma unroll
    for (int mi = 0; mi < MI; ++mi)
#pragma unroll
        for (int nj = 0; nj < NJ; ++nj) acc[mi][nj] = (f32x4){0.f, 0.f, 0.f, 0.f};

    STAGE(0, 0);

    for (int kt = 0; kt < NT; ++kt) {
        const int cur = kt & 1;
        __syncthreads();
        if (kt + 1 < NT) STAGE(cur ^ 1, kt + 1);
        const char* Ab = &lds[cur][0];
        const char* Bb = Ab + ABYTES;
        bf16x8 af[MI], bfr[NJ];
#pragma unroll
        for (int mi = 0; mi < MI; ++mi)
            af[mi] = *(const bf16x8*)(Ab + (wm * TM + mi * 16 + lc) * 64 + lg * 16);
#pragma unroll
        for (int nj = 0; nj < NJ; ++nj)
            bfr[nj] = *(const bf16x8*)(Bb + (wn * TN + nj * 16 + lc) * 64 + lg * 16);
#pragma unroll
        for (int mi = 0; mi < MI; ++mi)
#pragma unroll
            for (int nj = 0; nj < NJ; ++nj)
                acc[mi][nj] = __builtin_amdgcn_mfma_f32_16x16x32_bf16(af[mi], bfr[nj], acc[mi][nj], 0, 0, 0);
    }
#undef STAGE

    if constexpr (MODE == 0) {
        float* C = (float*)o0;
#pragma unroll
        for (int nj = 0; nj < NJ; ++nj) {
            const int n = nseg0 + wn * TN + nj * 16 + lc;
            const float bn = biasp[n];
#pragma unroll
            for (int mi = 0; mi < MI; ++mi)
#pragma unroll
                for (int r = 0; r < 4; ++r) {
                    const int m = m0 + wm * TM + mi * 16 + lg * 4 + r;
                    C[(size_t)m * DM_ + n] = acc[mi][nj][r] + bn;
                }
        }
    } else {
        if (seg < 2) {
            ushort* C = (seg == 0) ? (ushort*)o0 : (ushort*)o1;
#pragma unroll
            for (int nj = 0; nj < NJ; ++nj) {
                const int n = nseg0 + wn * TN + nj * 16 + lc;
                const float bn = biasp[n];
                const int i2 = (n & 63) & ~1;
                const bool odd = (n & 1) != 0;
#pragma unroll
                for (int mi = 0; mi < MI; ++mi)
#pragma unroll
                    for (int r = 0; r < 4; ++r) {
                        const int m = m0 + wm * TM + mi * 16 + lg * 4 + r;
                        const int s = m & (S_ - 1);
                        const float2 pz = *(const float2*)(pos + (size_t)s * DH_ + i2);
                        const float v = acc[mi][nj][r] + bn;
                        const float pv = __shfl_xor(v, 1);
                        float ov = odd ? (v * pz.y + pv * pz.x) : (v * pz.y - pv * pz.x);
                        if (seg == 0) ov *= QSCALE;
                        C[(size_t)m * (H_ * DH_) + n] = f2bf(ov);
                    }
            }
        } else {
            ushort* C = (ushort*)o2;
#pragma unroll
            for (int nj = 0; nj < NJ; ++nj) {
                const int n = nseg0 + wn * TN + nj * 16 + lc;
                const int hh = n >> 6, dd = n & 63;
                const float bn = biasp[n];
#pragma unroll
                for (int mi = 0; mi < MI; ++mi) {
                    const int mb = m0 + wm * TM + mi * 16 + lg * 4;
                    const int bb = mb >> 11, ss = mb & (S_ - 1);
                    ushort4 u;
                    u.x = f2bf(acc[mi][nj][0] + bn);
                    u.y = f2bf(acc[mi][nj][1] + bn);
                    u.z = f2bf(acc[mi][nj][2] + bn);
                    u.w = f2bf(acc[mi][nj][3] + bn);
                    *(ushort4*)(C + ((size_t)(bb * H_ + hh) * DH_ + dd) * S_ + ss) = u;
                }
            }
        }
    }
}

// ---------------------------------------------------------------------------
// bf16 MFMA flash attention — round 6: QK^T pipelined ONE TILE AHEAD.
// Iteration t: store tile t+1 -> LDS buf[(t+1)&1]; barrier; issue QK(t+1)
// MFMAs; softmax+PV of tile t overlap the MFMA pipe; barrier.
// No setprio (barrier-locked waves: m190 regime). Defer-max THR=12 (log2):
// rescale fires ~once per block; P <= 2^12, l <= 2^23 -> fp32-safe.
// ---------------------------------------------------------------------------
__global__ __launch_bounds__(256) void attn_mfma_kernel(
    const short* __restrict__ Qb, const short* __restrict__ Kb,
    const short* __restrict__ Vt, const int* __restrict__ vmask,
    ushort* __restrict__ O)
{
    __shared__ short Ks[2][64 * 64];
    __shared__ short Vs[2][64 * 64];
    __shared__ float bias_s[2][64];

    const int tid  = threadIdx.x;
    const int lane = tid & 63;
    const int w    = tid >> 6;
    const int c    = lane & 15;
    const int g    = lane >> 4;

    const int bid = blockIdx.x;          // b*512 + h*32 + qc
    const int qc = bid & 31;
    const int h  = (bid >> 5) & 15;
    const int b  = bid >> 9;
    const int s0 = qc * 64;

    bf16x8 qf[2];
    {
        const size_t qbase = ((size_t)(b * S_ + s0 + w * 16 + c)) * DM_ + h * DH_ + g * 8;
        qf[0] = *(const bf16x8*)(Qb + qbase);
        qf[1] = *(const bf16x8*)(Qb + qbase + 32);
    }

    const int kr0 = tid >> 3, kc0 = tid & 7;
    const int kr1 = kr0 + 32;
    const size_t kpan = ((size_t)b * S_) * DM_ + h * DH_;
    const size_t vpan = ((size_t)(b * H_ + h) * DH_) * S_;

    uint4 kv0, kv1, vv0, vv1;
    int mskv = 1;
    constexpr int NT = S_ / 64;

#define LOAD_TILE(KT)                                                            \
    do {                                                                         \
        const size_t kg = kpan + (size_t)((KT) * 64) * DM_;                      \
        kv0 = *(const uint4*)(Kb + kg + (size_t)kr0 * DM_ + kc0 * 8);            \
        kv1 = *(const uint4*)(Kb + kg + (size_t)kr1 * DM_ + kc0 * 8);            \
        const size_t vg = vpan + (KT) * 64;                                      \
        vv0 = *(const uint4*)(Vt + vg + (size_t)kr0 * S_ + kc0 * 8);             \
        vv1 = *(const uint4*)(Vt + vg + (size_t)kr1 * S_ + kc0 * 8);             \
        if (tid < 64) mskv = vmask[b * S_ + (KT) * 64 + tid];                    \
    } while (0)

#define STORE_TILE(BUF)                                                          \
    do {                                                                         \
        *(uint4*)&Ks[BUF][kr0 * 64 + ((kc0 ^ (kr0 & 7)) * 8)] = kv0;             \
        *(uint4*)&Ks[BUF][kr1 * 64 + ((kc0 ^ (kr1 & 7)) * 8)] = kv1;             \
        *(uint4*)&Vs[BUF][kr0 * 64 + ((kc0 ^ (kr0 & 7)) * 8)] = vv0;             \
        *(uint4*)&Vs[BUF][kr1 * 64 + ((kc0 ^ (kr1 & 7)) * 8)] = vv1;             \
        if (tid < 64) bias_s[BUF][tid] = mskv ? 0.f : NEGV;                      \
    } while (0)

// QK^T (swapped): ACC[km] = S^T[key=km*16+c][q], init with mask bias
#define QK_TILE(ACC, BUF)                                                        \
    do {                                                                         \
        _Pragma("unroll")                                                        \
        for (int km = 0; km < 4; ++km)                                           \
            ACC[km] = *(const f32x4*)&bias_s[BUF][km * 16 + g * 4];              \
        _Pragma("unroll")                                                        \
        for (int km = 0; km < 4; ++km) {                                         \
            const int krow = km * 16 + c;                                        \
            const int swz = krow & 7;                                            \
            _Pragma("unroll")                                                    \
            for (int t2 = 0; t2 < 2; ++t2) {                                     \
                const bf16x8 kf = *(const bf16x8*)&Ks[BUF][krow * 64 +           \
                                        (((t2 * 4 + g) ^ swz) * 8)];             \
                ACC[km] = __builtin_amdgcn_mfma_f32_16x16x32_bf16(               \
                              kf, qf[t2], ACC[km], 0, 0, 0);                     \
            }                                                                    \
        }                                                                        \
    } while (0)

// softmax (defer-max) + P->bf16 + bpermute redistribution + PV from Vs[BUF]
#define SOFTMAX_PV(ACC, BUF)                                                     \
    do {                                                                         \
        float pm = -1e30f;                                                       \
        _Pragma("unroll")                                                        \
        for (int km = 0; km < 4; ++km)                                           \
            _Pragma("unroll")                                                    \
            for (int r = 0; r < 4; ++r) pm = fmaxf(pm, ACC[km][r]);              \
        pm = fmaxf(pm, __shfl_xor(pm, 16));                                      \
        pm = fmaxf(pm, __shfl_xor(pm, 32));                                      \
        if (!__all(pm <= m_run + DEFER_THR)) {                                   \
            const float m_new = fmaxf(m_run, pm);                                \
            const float sc = exp2f(m_run - m_new);                               \
            _Pragma("unroll")                                                    \
            for (int r = 0; r < 4; ++r) {                                        \
                const float scr = __shfl(sc, (lane & 48) | (g * 4 + r));         \
                _Pragma("unroll")                                                \
                for (int dg = 0; dg < 4; ++dg) acc_o[dg][r] *= scr;              \
            }                                                                    \
            l_run *= sc;                                                         \
            m_run = m_new;                                                       \
        }                                                                        \
        float p[16];                                                             \
        float tsum = 0.f;                                                        \
        _Pragma("unroll")                                                        \
        for (int km = 0; km < 4; ++km)                                           \
            _Pragma("unroll")                                                    \
            for (int r = 0; r < 4; ++r) {                                        \
                const float e = exp2f(ACC[km][r] - m_run);                       \
                p[km * 4 + r] = e;                                               \
                tsum += e;                                                       \
            }                                                                    \
        tsum += __shfl_xor(tsum, 16);                                            \
        tsum += __shfl_xor(tsum, 32);                                            \
        l_run += tsum;                                                           \
        uint32_t pk[4][2];                                                       \
        _Pragma("unroll")                                                        \
        for (int km = 0; km < 4; ++km) {                                         \
            pk[km][0] = cvt_pk_bf16(p[km * 4 + 0], p[km * 4 + 1]);               \
            pk[km][1] = cvt_pk_bf16(p[km * 4 + 2], p[km * 4 + 3]);               \
        }                                                                        \
        _Pragma("unroll")                                                        \
        for (int t2 = 0; t2 < 2; ++t2) {                                         \
            uint32_t fw[4];                                                      \
            _Pragma("unroll")                                                    \
            for (int w2 = 0; w2 < 4; ++w2) {                                     \
                const int src = (w2 < 2) ? srcA : srcB;                          \
                const uint32_t vlo = (uint32_t)__builtin_amdgcn_ds_bpermute(     \
                    src, (int)pk[2 * t2][w2 & 1]);                               \
                const uint32_t vhi = (uint32_t)__builtin_amdgcn_ds_bpermute(     \
                    src, (int)pk[2 * t2 + 1][w2 & 1]);                           \
                fw[w2] = hiSel ? vhi : vlo;                                      \
            }                                                                    \
            union { uint32_t u[4]; bf16x8 v; } pf;                               \
            pf.u[0] = fw[0]; pf.u[1] = fw[1]; pf.u[2] = fw[2]; pf.u[3] = fw[3];  \
            _Pragma("unroll")                                                    \
            for (int dg = 0; dg < 4; ++dg) {                                     \
                const int vrow = dg * 16 + c;                                    \
                const bf16x8 vf = *(const bf16x8*)&Vs[BUF][vrow * 64 +           \
                                        (((t2 * 4 + g) ^ (vrow & 7)) * 8)];      \
                acc_o[dg] = __builtin_amdgcn_mfma_f32_16x16x32_bf16(             \
                                pf.v, vf, acc_o[dg], 0, 0, 0);                   \
            }                                                                    \
        }                                                                        \
    } while (0)

    float m_run = -1e30f, l_run = 0.f;
    f32x4 acc_o[4];
#pragma unroll
    for (int dg = 0; dg < 4; ++dg) acc_o[dg] = (f32x4){0.f, 0.f, 0.f, 0.f};

    const int srcA = ((((g & 1) * 2) << 4) + c) * 4;
    const int srcB = ((((g & 1) * 2 + 1) << 4) + c) * 4;
    const bool hiSel = (lane >= 32);

    // ---- prologue: tile 0 into buf0, QK(0)
    LOAD_TILE(0);
    STORE_TILE(0);
    __syncthreads();
    LOAD_TILE(1);
    f32x4 acc_t[4];
    QK_TILE(acc_t, 0);

    // ---- main loop: iteration kt issues QK(kt+1), finishes tile kt
    for (int kt = 0; kt < NT - 1; ++kt) {
        const int cur = kt & 1, nxt = cur ^ 1;
        STORE_TILE(nxt);                       // regs hold tile kt+1
        __syncthreads();
        if (kt + 2 < NT) LOAD_TILE(kt + 2);    // prefetch tile kt+2 into regs
        f32x4 acc_n[4];
        QK_TILE(acc_n, nxt);                   // MFMA pipe: scores(kt+1)
        SOFTMAX_PV(acc_t, cur);                // VALU overlaps MFMA above
#pragma unroll
        for (int km = 0; km < 4; ++km) acc_t[km] = acc_n[km];
        __syncthreads();                       // protect buf[cur] before overwrite
    }
    // ---- epilogue: finish last tile
    SOFTMAX_PV(acc_t, (NT - 1) & 1);

#undef LOAD_TILE
#undef STORE_TILE
#undef QK_TILE
#undef SOFTMAX_PV

    const float linv = 1.0f / l_run;
#pragma unroll
    for (int r = 0; r < 4; ++r) {
        const float lr = __shfl(linv, (lane & 48) | (g * 4 + r));
        const int row = s0 + w * 16 + g * 4 + r;
        const size_t ob = ((size_t)(b * S_ + row)) * DM_ + h * DH_;
#pragma unroll
        for (int dg = 0; dg < 4; ++dg)
            O[ob + dg * 16 + c] = f2bf(acc_o[dg][r] * lr);
    }
}

// ---------------------------------------------------------------------------
extern "C" void kernel_launch(void* const* d_in, const int* in_sizes, int n_in,
                              void* d_out, int out_size, void* d_ws, size_t ws_size,
                              hipStream_t stream)
{
    const float* x     = (const float*)d_in[0];
    const int*   vmask = (const int*)d_in[1];
    const float* pos   = (const float*)d_in[2];
    const float* Wq    = (const float*)d_in[3];
    const float* bq    = (const float*)d_in[4];
    const float* Wk    = (const float*)d_in[5];
    const float* bk    = (const float*)d_in[6];
    const float* Wv    = (const float*)d_in[7];
    const float* bv    = (const float*)d_in[8];
    const float* Wo    = (const float*)d_in[9];
    const float* bo    = (const float*)d_in[10];
    float* out = (float*)d_out;

    const size_t MN = (size_t)(B_ * S_) * (H_ * DH_);   // 4M

    ushort* xb  = (ushort*)d_ws;          // 8 MB
    ushort* Wtq = xb + MN;                // 2 MB each
    ushort* Wtk = Wtq + 1024 * 1024;
    ushort* Wtv = Wtk + 1024 * 1024;
    ushort* Wto = Wtv + 1024 * 1024;
    ushort* Qb  = Wto + 1024 * 1024;      // 8 MB each
    ushort* Kb  = Qb + MN;
    ushort* Vt  = Kb + MN;
    ushort* Ob  = Vt + MN;

    convx_kernel<<<(int)(MN / 2048), 256, 0, stream>>>(x, xb);
    wconv_kernel<<<256, 256, 0, stream>>>(Wq, Wtq);
    wconv_kernel<<<256, 256, 0, stream>>>(Wk, Wtk);
    wconv_kernel<<<256, 256, 0, stream>>>(Wv, Wtv);
    wconv_kernel<<<256, 256, 0, stream>>>(Wo, Wto);

    // fused QKV: grid = (4096/128) m-tiles x 24 n-tiles = 768 blocks (3/CU)
    gemm_bf16<1><<<768, 256, 0, stream>>>(xb, Wtq, Wtk, Wtv, bq, bk, bv, pos,
                                          (void*)Qb, (void*)Kb, (void*)Vt);

    attn_mfma_kernel<<<B_ * H_ * (S_ / 64), 256, 0, stream>>>(
        (const short*)Qb, (const short*)Kb, (const short*)Vt, vmask, Ob);

    // out-proj: grid = (4096/64) x 8 = 512 blocks (2/CU)
    gemm_bf16<0><<<512, 256, 0, stream>>>(Ob, Wto, nullptr, nullptr, bo, nullptr, nullptr,
                                          nullptr, (void*)out, nullptr, nullptr);
}

// Round 7
// 171.206 us; speedup vs baseline: 1.1778x; 1.1389x over previous
//
#include <hip/hip_runtime.h>
#include <cstddef>
#include <cstdint>

#define B_ 2
#define S_ 2048
#define DM_ 1024
#define H_ 16
#define DH_ 64
#define NEGV (-1e12f)
// log2(e) / sqrt(DH) folded into Q at projection epilogue
#define QSCALE 0.18033688011112042f
// defer-max threshold in log2 units: P <= 2^12, l <= 2048*4096 -> fp32-safe
#define DEFER_THR 12.0f

typedef __attribute__((ext_vector_type(8))) short bf16x8;
typedef __attribute__((ext_vector_type(4))) float f32x4;

__device__ __forceinline__ unsigned short f2bf(float f) {
    union { float f; uint32_t u; } v; v.f = f;
    uint32_t u = v.u;
    u += 0x7FFF + ((u >> 16) & 1);   // round-to-nearest-even
    return (unsigned short)(u >> 16);
}

// packed f32x2 -> bf16x2 (RNE), single HW instruction (T12 recipe)
__device__ __forceinline__ uint32_t cvt_pk_bf16(float lo, float hi) {
    uint32_t r;
    asm volatile("v_cvt_pk_bf16_f32 %0, %1, %2" : "=v"(r) : "v"(lo), "v"(hi));
    return r;
}

__device__ __forceinline__ void gload_lds16(const void* g, void* l) {
    __builtin_amdgcn_global_load_lds(
        (__attribute__((address_space(1))) void*)g,
        (__attribute__((address_space(3))) void*)l,
        16, 0, 0);
}

// ---------------------------------------------------------------------------
// x (fp32) -> bf16, flat
// ---------------------------------------------------------------------------
__global__ __launch_bounds__(256) void convx_kernel(
    const float* __restrict__ x, ushort* __restrict__ xb)
{
    const size_t i = ((size_t)blockIdx.x * 256 + threadIdx.x) * 8;
    const float4 a = *(const float4*)(x + i);
    const float4 b = *(const float4*)(x + i + 4);
    ushort4 u0, u1;
    u0.x = f2bf(a.x); u0.y = f2bf(a.y); u0.z = f2bf(a.z); u0.w = f2bf(a.w);
    u1.x = f2bf(b.x); u1.y = f2bf(b.y); u1.z = f2bf(b.z); u1.w = f2bf(b.w);
    *(ushort4*)(xb + i) = u0;
    *(ushort4*)(xb + i + 4) = u1;
}

// ---------------------------------------------------------------------------
// batched: W[k][n] fp32 -> Wt[n][k] bf16 for all 4 weights in one launch
// ---------------------------------------------------------------------------
__global__ __launch_bounds__(256) void wconv_all_kernel(
    const float* __restrict__ W0, const float* __restrict__ W1,
    const float* __restrict__ W2, const float* __restrict__ W3,
    ushort* __restrict__ T0, ushort* __restrict__ T1,
    ushort* __restrict__ T2, ushort* __restrict__ T3)
{
    __shared__ float T[64][65];
    const int tid = threadIdx.x;
    const int sel = blockIdx.x >> 8;
    const int bt  = blockIdx.x & 255;
    const float* W = (sel == 0) ? W0 : (sel == 1) ? W1 : (sel == 2) ? W2 : W3;
    ushort* Wt = (sel == 0) ? T0 : (sel == 1) ? T1 : (sel == 2) ? T2 : T3;

    const int n0 = (bt & 15) * 64;
    const int k0 = (bt >> 4) * 64;
    const int tr = tid >> 4, tc = tid & 15;
#pragma unroll
    for (int i = 0; i < 4; ++i) {
        const float4 v = *(const float4*)(W + (size_t)(k0 + tr + i * 16) * 1024 + n0 + tc * 4);
        T[tr + i * 16][tc * 4 + 0] = v.x;
        T[tr + i * 16][tc * 4 + 1] = v.y;
        T[tr + i * 16][tc * 4 + 2] = v.z;
        T[tr + i * 16][tc * 4 + 3] = v.w;
    }
    __syncthreads();
    const int orr = tid >> 2, oc = tid & 3;
#pragma unroll
    for (int j = 0; j < 4; ++j) {
        ushort4 u;
        u.x = f2bf(T[oc * 16 + j * 4 + 0][orr]);
        u.y = f2bf(T[oc * 16 + j * 4 + 1][orr]);
        u.z = f2bf(T[oc * 16 + j * 4 + 2][orr]);
        u.w = f2bf(T[oc * 16 + j * 4 + 3][orr]);
        *(ushort4*)(Wt + (size_t)(n0 + orr) * 1024 + k0 + oc * 16 + j * 4) = u;
    }
}

// ---------------------------------------------------------------------------
// bf16 MFMA GEMM, C = A @ Bt^T (+bias, +epilogue). A[M][1024], Bt[n][1024].
// MODE 1: fused QKV (BM=128, Ntot=3072 in 3 segments; rope epilogues, V transp)
// MODE 0: out-proj  (BM=64, N=1024, fp32 out)
// (unchanged — validated)
// ---------------------------------------------------------------------------
template <int MODE>
__global__ __launch_bounds__(256) void gemm_bf16(
    const ushort* __restrict__ A,
    const ushort* __restrict__ B0, const ushort* __restrict__ B1, const ushort* __restrict__ B2,
    const float* __restrict__ bias0, const float* __restrict__ bias1, const float* __restrict__ bias2,
    const float* __restrict__ pos,
    void* __restrict__ o0, void* __restrict__ o1, void* __restrict__ o2)
{
    constexpr int BM = MODE ? 128 : 64;
    constexpr int BN = 128;
    constexpr int NTN = MODE ? 24 : 8;
    constexpr int A_ISS = BM / 64;
    constexpr int ABYTES = BM * 64;
    constexpr int WM = MODE ? 2 : 1;
    constexpr int TM = BM / WM;
    constexpr int TN = BN / (4 / WM);
    constexpr int MI = TM / 16;
    constexpr int NJ = TN / 16;
    constexpr int NT = DM_ / 32;

    __shared__ char lds[2][(BM + BN) * 64];

    const int tid  = threadIdx.x;
    const int lane = tid & 63;
    const int lc = lane & 15, lg = lane >> 4;
    const int w  = tid >> 6;
    const int wm = MODE ? (w >> 1) : 0;
    const int wn = MODE ? (w & 1) : w;

    const int ntile = blockIdx.x % NTN;
    const int mtile = blockIdx.x / NTN;
    const int m0 = mtile * BM;

    int seg = 0, nseg0 = ntile * 128;
    const ushort* Bt = B0;
    const float* biasp = bias0;
    if constexpr (MODE == 1) {
        seg = ntile >> 3;
        nseg0 = (ntile & 7) * 128;
        Bt = (seg == 0) ? B0 : (seg == 1) ? B1 : B2;
        biasp = (seg == 0) ? bias0 : (seg == 1) ? bias1 : bias2;
    }

    const int sr = tid >> 2;
    const int sc = (tid & 3) * 8;
    const int wub = (tid & 0xC0) * 16;

#define STAGE(BUF, KT)                                                             \
    do {                                                                           \
        const int k0s = (KT) * 32;                                                 \
        char* lb = &lds[BUF][0];                                                   \
        _Pragma("unroll")                                                          \
        for (int ii = 0; ii < A_ISS; ++ii)                                         \
            gload_lds16(A + (size_t)(m0 + ii * 64 + sr) * DM_ + k0s + sc,          \
                        lb + ii * 4096 + wub);                                     \
        _Pragma("unroll")                                                          \
        for (int ii = 0; ii < 2; ++ii)                                             \
            gload_lds16(Bt + (size_t)(nseg0 + ii * 64 + sr) * DM_ + k0s + sc,      \
                        lb + ABYTES + ii * 4096 + wub);                            \
    } while (0)

    f32x4 acc[MI][NJ];
#pragma unroll
    for (int mi = 0; mi < MI; ++mi)
#pragma unroll
        for (int nj = 0; nj < NJ; ++nj) acc[mi][nj] = (f32x4){0.f, 0.f, 0.f, 0.f};

    STAGE(0, 0);

    for (int kt = 0; kt < NT; ++kt) {
        const int cur = kt & 1;
        __syncthreads();
        if (kt + 1 < NT) STAGE(cur ^ 1, kt + 1);
        const char* Ab = &lds[cur][0];
        const char* Bb = Ab + ABYTES;
        bf16x8 af[MI], bfr[NJ];
#pragma unroll
        for (int mi = 0; mi < MI; ++mi)
            af[mi] = *(const bf16x8*)(Ab + (wm * TM + mi * 16 + lc) * 64 + lg * 16);
#pragma unroll
        for (int nj = 0; nj < NJ; ++nj)
            bfr[nj] = *(const bf16x8*)(Bb + (wn * TN + nj * 16 + lc) * 64 + lg * 16);
#pragma unroll
        for (int mi = 0; mi < MI; ++mi)
#pragma unroll
            for (int nj = 0; nj < NJ; ++nj)
                acc[mi][nj] = __builtin_amdgcn_mfma_f32_16x16x32_bf16(af[mi], bfr[nj], acc[mi][nj], 0, 0, 0);
    }
#undef STAGE

    if constexpr (MODE == 0) {
        float* C = (float*)o0;
#pragma unroll
        for (int nj = 0; nj < NJ; ++nj) {
            const int n = nseg0 + wn * TN + nj * 16 + lc;
            const float bn = biasp[n];
#pragma unroll
            for (int mi = 0; mi < MI; ++mi)
#pragma unroll
                for (int r = 0; r < 4; ++r) {
                    const int m = m0 + wm * TM + mi * 16 + lg * 4 + r;
                    C[(size_t)m * DM_ + n] = acc[mi][nj][r] + bn;
                }
        }
    } else {
        if (seg < 2) {
            ushort* C = (seg == 0) ? (ushort*)o0 : (ushort*)o1;
#pragma unroll
            for (int nj = 0; nj < NJ; ++nj) {
                const int n = nseg0 + wn * TN + nj * 16 + lc;
                const float bn = biasp[n];
                const int i2 = (n & 63) & ~1;
                const bool odd = (n & 1) != 0;
#pragma unroll
                for (int mi = 0; mi < MI; ++mi)
#pragma unroll
                    for (int r = 0; r < 4; ++r) {
                        const int m = m0 + wm * TM + mi * 16 + lg * 4 + r;
                        const int s = m & (S_ - 1);
                        const float2 pz = *(const float2*)(pos + (size_t)s * DH_ + i2);
                        const float v = acc[mi][nj][r] + bn;
                        const float pv = __shfl_xor(v, 1);
                        float ov = odd ? (v * pz.y + pv * pz.x) : (v * pz.y - pv * pz.x);
                        if (seg == 0) ov *= QSCALE;
                        C[(size_t)m * (H_ * DH_) + n] = f2bf(ov);
                    }
            }
        } else {
            ushort* C = (ushort*)o2;
#pragma unroll
            for (int nj = 0; nj < NJ; ++nj) {
                const int n = nseg0 + wn * TN + nj * 16 + lc;
                const int hh = n >> 6, dd = n & 63;
                const float bn = biasp[n];
#pragma unroll
                for (int mi = 0; mi < MI; ++mi) {
                    const int mb = m0 + wm * TM + mi * 16 + lg * 4;
                    const int bb = mb >> 11, ss = mb & (S_ - 1);
                    ushort4 u;
                    u.x = f2bf(acc[mi][nj][0] + bn);
                    u.y = f2bf(acc[mi][nj][1] + bn);
                    u.z = f2bf(acc[mi][nj][2] + bn);
                    u.w = f2bf(acc[mi][nj][3] + bn);
                    *(ushort4*)(C + ((size_t)(bb * H_ + hh) * DH_ + dd) * S_ + ss) = u;
                }
            }
        }
    }
}

// ---------------------------------------------------------------------------
// bf16 MFMA flash attention — round 7: 8 waves / 128 q-rows per block.
// K/V LDS tile (16KB/tile) now amortized over 8 waves instead of 4:
// LDS-read traffic, staging, barriers and HBM K/V refetch all halve per q.
// Same QK^T-one-tile-ahead pipeline and double-buffer race-freedom proof.
// ---------------------------------------------------------------------------
__global__ __launch_bounds__(512) void attn_mfma_kernel(
    const short* __restrict__ Qb, const short* __restrict__ Kb,
    const short* __restrict__ Vt, const int* __restrict__ vmask,
    ushort* __restrict__ O)
{
    __shared__ short Ks[2][64 * 64];
    __shared__ short Vs[2][64 * 64];
    __shared__ float bias_s[2][64];

    const int tid  = threadIdx.x;
    const int lane = tid & 63;
    const int w    = tid >> 6;        // 0..7
    const int c    = lane & 15;
    const int g    = lane >> 4;

    const int bid = blockIdx.x;       // b*256 + h*16 + qc  (qc low: L2 reuse)
    const int qc = bid & 15;
    const int h  = (bid >> 4) & 15;
    const int b  = bid >> 8;
    const int s0 = qc * 128;

    // Q fragments (B-operand): lane holds Q[q = w*16 + c][k = g*8 + j]
    bf16x8 qf[2];
    {
        const size_t qbase = ((size_t)(b * S_ + s0 + w * 16 + c)) * DM_ + h * DH_ + g * 8;
        qf[0] = *(const bf16x8*)(Qb + qbase);
        qf[1] = *(const bf16x8*)(Qb + qbase + 32);
    }

    // staging: 512 threads, one 16B chunk per thread per matrix
    const int kr0 = tid >> 3, kc0 = tid & 7;
    const size_t kpan = ((size_t)b * S_) * DM_ + h * DH_;
    const size_t vpan = ((size_t)(b * H_ + h) * DH_) * S_;

    uint4 kv0, vv0;
    int mskv = 1;
    constexpr int NT = S_ / 64;

#define LOAD_TILE(KT)                                                            \
    do {                                                                         \
        kv0 = *(const uint4*)(Kb + kpan + (size_t)((KT) * 64 + kr0) * DM_ + kc0 * 8); \
        vv0 = *(const uint4*)(Vt + vpan + (size_t)kr0 * S_ + (KT) * 64 + kc0 * 8);    \
        if (tid < 64) mskv = vmask[b * S_ + (KT) * 64 + tid];                    \
    } while (0)

#define STORE_TILE(BUF)                                                          \
    do {                                                                         \
        *(uint4*)&Ks[BUF][kr0 * 64 + ((kc0 ^ (kr0 & 7)) * 8)] = kv0;             \
        *(uint4*)&Vs[BUF][kr0 * 64 + ((kc0 ^ (kr0 & 7)) * 8)] = vv0;             \
        if (tid < 64) bias_s[BUF][tid] = mskv ? 0.f : NEGV;                      \
    } while (0)

// QK^T (swapped): ACC[km] = S^T[key=km*16+...][q], init with mask bias
#define QK_TILE(ACC, BUF)                                                        \
    do {                                                                         \
        _Pragma("unroll")                                                        \
        for (int km = 0; km < 4; ++km)                                           \
            ACC[km] = *(const f32x4*)&bias_s[BUF][km * 16 + g * 4];              \
        _Pragma("unroll")                                                        \
        for (int km = 0; km < 4; ++km) {                                         \
            const int krow = km * 16 + c;                                        \
            const int swz = krow & 7;                                            \
            _Pragma("unroll")                                                    \
            for (int t2 = 0; t2 < 2; ++t2) {                                     \
                const bf16x8 kf = *(const bf16x8*)&Ks[BUF][krow * 64 +           \
                                        (((t2 * 4 + g) ^ swz) * 8)];             \
                ACC[km] = __builtin_amdgcn_mfma_f32_16x16x32_bf16(               \
                              kf, qf[t2], ACC[km], 0, 0, 0);                     \
            }                                                                    \
        }                                                                        \
    } while (0)

// softmax (defer-max) + P->bf16 + bpermute redistribution + PV from Vs[BUF]
#define SOFTMAX_PV(ACC, BUF)                                                     \
    do {                                                                         \
        float pm = -1e30f;                                                       \
        _Pragma("unroll")                                                        \
        for (int km = 0; km < 4; ++km)                                           \
            _Pragma("unroll")                                                    \
            for (int r = 0; r < 4; ++r) pm = fmaxf(pm, ACC[km][r]);              \
        pm = fmaxf(pm, __shfl_xor(pm, 16));                                      \
        pm = fmaxf(pm, __shfl_xor(pm, 32));                                      \
        if (!__all(pm <= m_run + DEFER_THR)) {                                   \
            const float m_new = fmaxf(m_run, pm);                                \
            const float sc = exp2f(m_run - m_new);                               \
            _Pragma("unroll")                                                    \
            for (int r = 0; r < 4; ++r) {                                        \
                const float scr = __shfl(sc, (lane & 48) | (g * 4 + r));         \
                _Pragma("unroll")                                                \
                for (int dg = 0; dg < 4; ++dg) acc_o[dg][r] *= scr;              \
            }                                                                    \
            l_run *= sc;                                                         \
            m_run = m_new;                                                       \
        }                                                                        \
        float p[16];                                                             \
        float tsum = 0.f;                                                        \
        _Pragma("unroll")                                                        \
        for (int km = 0; km < 4; ++km)                                           \
            _Pragma("unroll")                                                    \
            for (int r = 0; r < 4; ++r) {                                        \
                const float e = exp2f(ACC[km][r] - m_run);                       \
                p[km * 4 + r] = e;                                               \
                tsum += e;                                                       \
            }                                                                    \
        tsum += __shfl_xor(tsum, 16);                                            \
        tsum += __shfl_xor(tsum, 32);                                            \
        l_run += tsum;                                                           \
        uint32_t pk[4][2];                                                       \
        _Pragma("unroll")                                                        \
        for (int km = 0; km < 4; ++km) {                                         \
            pk[km][0] = cvt_pk_bf16(p[km * 4 + 0], p[km * 4 + 1]);               \
            pk[km][1] = cvt_pk_bf16(p[km * 4 + 2], p[km * 4 + 3]);               \
        }                                                                        \
        _Pragma("unroll")                                                        \
        for (int t2 = 0; t2 < 2; ++t2) {                                         \
            uint32_t fw[4];                                                      \
            _Pragma("unroll")                                                    \
            for (int w2 = 0; w2 < 4; ++w2) {                                     \
                const int src = (w2 < 2) ? srcA : srcB;                          \
                const uint32_t vlo = (uint32_t)__builtin_amdgcn_ds_bpermute(     \
                    src, (int)pk[2 * t2][w2 & 1]);                               \
                const uint32_t vhi = (uint32_t)__builtin_amdgcn_ds_bpermute(     \
                    src, (int)pk[2 * t2 + 1][w2 & 1]);                           \
                fw[w2] = hiSel ? vhi : vlo;                                      \
            }                                                                    \
            union { uint32_t u[4]; bf16x8 v; } pf;                               \
            pf.u[0] = fw[0]; pf.u[1] = fw[1]; pf.u[2] = fw[2]; pf.u[3] = fw[3];  \
            _Pragma("unroll")                                                    \
            for (int dg = 0; dg < 4; ++dg) {                                     \
                const int vrow = dg * 16 + c;                                    \
                const bf16x8 vf = *(const bf16x8*)&Vs[BUF][vrow * 64 +           \
                                        (((t2 * 4 + g) ^ (vrow & 7)) * 8)];      \
                acc_o[dg] = __builtin_amdgcn_mfma_f32_16x16x32_bf16(             \
                                pf.v, vf, acc_o[dg], 0, 0, 0);                   \
            }                                                                    \
        }                                                                        \
    } while (0)

    float m_run = -1e30f, l_run = 0.f;
    f32x4 acc_o[4];
#pragma unroll
    for (int dg = 0; dg < 4; ++dg) acc_o[dg] = (f32x4){0.f, 0.f, 0.f, 0.f};

    const int srcA = ((((g & 1) * 2) << 4) + c) * 4;
    const int srcB = ((((g & 1) * 2 + 1) << 4) + c) * 4;
    const bool hiSel = (lane >= 32);

    // ---- prologue: tile 0 into buf0, QK(0)
    LOAD_TILE(0);
    STORE_TILE(0);
    __syncthreads();
    LOAD_TILE(1);
    f32x4 acc_t[4];
    QK_TILE(acc_t, 0);

    // ---- main loop: iteration kt issues QK(kt+1), finishes tile kt
#pragma unroll 2
    for (int kt = 0; kt < NT - 1; ++kt) {
        const int cur = kt & 1, nxt = cur ^ 1;
        STORE_TILE(nxt);                       // regs hold tile kt+1
        __syncthreads();
        if (kt + 2 < NT) LOAD_TILE(kt + 2);    // prefetch tile kt+2 into regs
        f32x4 acc_n[4];
        QK_TILE(acc_n, nxt);                   // MFMA pipe: scores(kt+1)
        SOFTMAX_PV(acc_t, cur);                // VALU overlaps MFMA above
#pragma unroll
        for (int km = 0; km < 4; ++km) acc_t[km] = acc_n[km];
        __syncthreads();                       // protect buf[cur] before overwrite
    }
    // ---- epilogue: finish last tile
    SOFTMAX_PV(acc_t, (NT - 1) & 1);

#undef LOAD_TILE
#undef STORE_TILE
#undef QK_TILE
#undef SOFTMAX_PV

    const float linv = 1.0f / l_run;
#pragma unroll
    for (int r = 0; r < 4; ++r) {
        const float lr = __shfl(linv, (lane & 48) | (g * 4 + r));
        const int row = s0 + w * 16 + g * 4 + r;
        const size_t ob = ((size_t)(b * S_ + row)) * DM_ + h * DH_;
#pragma unroll
        for (int dg = 0; dg < 4; ++dg)
            O[ob + dg * 16 + c] = f2bf(acc_o[dg][r] * lr);
    }
}

// ---------------------------------------------------------------------------
extern "C" void kernel_launch(void* const* d_in, const int* in_sizes, int n_in,
                              void* d_out, int out_size, void* d_ws, size_t ws_size,
                              hipStream_t stream)
{
    const float* x     = (const float*)d_in[0];
    const int*   vmask = (const int*)d_in[1];
    const float* pos   = (const float*)d_in[2];
    const float* Wq    = (const float*)d_in[3];
    const float* bq    = (const float*)d_in[4];
    const float* Wk    = (const float*)d_in[5];
    const float* bk    = (const float*)d_in[6];
    const float* Wv    = (const float*)d_in[7];
    const float* bv    = (const float*)d_in[8];
    const float* Wo    = (const float*)d_in[9];
    const float* bo    = (const float*)d_in[10];
    float* out = (float*)d_out;

    const size_t MN = (size_t)(B_ * S_) * (H_ * DH_);   // 4M

    ushort* xb  = (ushort*)d_ws;          // 8 MB
    ushort* Wtq = xb + MN;                // 2 MB each
    ushort* Wtk = Wtq + 1024 * 1024;
    ushort* Wtv = Wtk + 1024 * 1024;
    ushort* Wto = Wtv + 1024 * 1024;
    ushort* Qb  = Wto + 1024 * 1024;      // 8 MB each
    ushort* Kb  = Qb + MN;
    ushort* Vt  = Kb + MN;
    ushort* Ob  = Vt + MN;

    convx_kernel<<<(int)(MN / 2048), 256, 0, stream>>>(x, xb);
    wconv_all_kernel<<<1024, 256, 0, stream>>>(Wq, Wk, Wv, Wo, Wtq, Wtk, Wtv, Wto);

    // fused QKV: grid = (4096/128) m-tiles x 24 n-tiles = 768 blocks (3/CU)
    gemm_bf16<1><<<768, 256, 0, stream>>>(xb, Wtq, Wtk, Wtv, bq, bk, bv, pos,
                                          (void*)Qb, (void*)Kb, (void*)Vt);

    // attention: 512 blocks x 512 threads (128 q-rows per block)
    attn_mfma_kernel<<<B_ * H_ * (S_ / 128), 512, 0, stream>>>(
        (const short*)Qb, (const short*)Kb, (const short*)Vt, vmask, Ob);

    // out-proj: grid = (4096/64) x 8 = 512 blocks (2/CU)
    gemm_bf16<0><<<512, 256, 0, stream>>>(Ob, Wto, nullptr, nullptr, bo, nullptr, nullptr,
                                          nullptr, (void*)out, nullptr, nullptr);
}